// Round 10
// baseline (251.086 us; speedup 1.0000x reference)
//
#include <hip/hip_runtime.h>
#include <math.h>

// Problem constants (fixed by setup_inputs)
#define BN_ 16
#define C_ 128
#define H_ 64
#define W_ 64
#define G_ 4
#define HS_ 128
#define WS_ 128
#define CG_ 32
#define HW_ (H_*W_)       // 4096
#define HWS_ (HS_*WS_)    // 16384
#define NOFF_ (BN_*8*HW_) // 524288

// ---------------------------------------------------------------------------
// Kernel 0: fold BN into 1x1 weights, transpose to [k][co]; fused bias
// ---------------------------------------------------------------------------
__global__ void prep_w(const float* __restrict__ w_proj, const float* __restrict__ g,
                       const float* __restrict__ be, const float* __restrict__ mean,
                       const float* __restrict__ var, float* __restrict__ wT,
                       float* __restrict__ b2) {
    int i = blockIdx.x * 256 + threadIdx.x;
    if (i < C_ * C_) {
        int k = i >> 7, co = i & 127;
        float a = g[co] / sqrtf(var[co] + 1e-5f);
        wT[i] = w_proj[co * C_ + k] * a;
    } else if (i < C_ * C_ + C_) {
        int co = i - C_ * C_;
        float a = g[co] / sqrtf(var[co] + 1e-5f);
        b2[co] = be[co] - mean[co] * a;
    }
}

// ---------------------------------------------------------------------------
// Kernel 1: 3x3 conv (offset branch). Unchanged from R8 (passed, ~15 µs model).
// ---------------------------------------------------------------------------
__global__ __launch_bounds__(256) void conv_off(const float* __restrict__ x,
                                                const float* __restrict__ w_off,
                                                float* __restrict__ part) {
    int bx = blockIdx.x;
    int cc = bx & 7;
    int rt = (bx >> 3) & 7;
    int b  = bx >> 6;
    int t  = threadIdx.x;
    int row = t >> 5;             // 0..7
    int cb  = (t & 31) * 2;       // 0..62

    __shared__ float xs[8][10][66];
    __shared__ float wsh[8][9][8];   // [ch][tap][co]

    float acc[8][2];
#pragma unroll
    for (int i = 0; i < 8; ++i) { acc[i][0] = 0.f; acc[i][1] = 0.f; }

    int row0 = rt * 8;
    int ch_s = (t >> 4) & 7;
    int q_s  = t & 15;
    int rbase = (t >> 7) * 5;

    for (int sub = 0; sub < 2; ++sub) {
        int cbase = cc * 16 + sub * 8;
        __syncthreads();
#pragma unroll
        for (int it = 0; it < 5; ++it) {
            int r = rbase + it;              // 0..9
            int grow = row0 + r - 1;
            float4 v = make_float4(0.f, 0.f, 0.f, 0.f);
            if (grow >= 0 && grow < H_)
                v = *(const float4*)&x[((size_t)(b * C_ + cbase + ch_s) * H_ + grow) * W_ + q_s * 4];
            xs[ch_s][r][1 + q_s * 4] = v.x;
            xs[ch_s][r][2 + q_s * 4] = v.y;
            xs[ch_s][r][3 + q_s * 4] = v.z;
            xs[ch_s][r][4 + q_s * 4] = v.w;
        }
        if (t < 128) {
            int ch2 = t >> 4, r2 = t & 15;
            if (r2 < 10) { xs[ch2][r2][0] = 0.f; xs[ch2][r2][65] = 0.f; }
        }
        for (int i = t; i < 576; i += 256) {
            int co  = i & 7;
            int tap = (i >> 3) % 9;
            int ch3 = (i >> 3) / 9;
            wsh[ch3][tap][co] = w_off[(co * C_ + cbase + ch3) * 9 + tap];
        }
        __syncthreads();
#pragma unroll
        for (int ch = 0; ch < 8; ++ch) {
#pragma unroll
            for (int ky = 0; ky < 3; ++ky) {
                float2 xv01 = *(float2*)&xs[ch][row + ky][cb];
                float2 xv23 = *(float2*)&xs[ch][row + ky][cb + 2];
                float xa[4] = {xv01.x, xv01.y, xv23.x, xv23.y};
#pragma unroll
                for (int kx = 0; kx < 3; ++kx) {
                    float4 w0 = *(float4*)&wsh[ch][ky * 3 + kx][0];
                    float4 w1 = *(float4*)&wsh[ch][ky * 3 + kx][4];
                    float wv[8] = {w0.x, w0.y, w0.z, w0.w, w1.x, w1.y, w1.z, w1.w};
                    float x0 = xa[kx], x1 = xa[kx + 1];
#pragma unroll
                    for (int co = 0; co < 8; ++co) {
                        acc[co][0] += x0 * wv[co];
                        acc[co][1] += x1 * wv[co];
                    }
                }
            }
        }
    }
#pragma unroll
    for (int co = 0; co < 8; ++co) {
        float2 v = make_float2(acc[co][0], acc[co][1]);
        *(float2*)&part[((size_t)(cc * BN_ + b) * 8 + co) * HW_ + (row0 + row) * W_ + cb] = v;
    }
}

// ---------------------------------------------------------------------------
// Kernel 2: reduce 8 partials + bias + tanh -> off
// ---------------------------------------------------------------------------
__global__ void off_reduce(const float* __restrict__ part, const float* __restrict__ b_off,
                           float* __restrict__ off) {
    int i = (blockIdx.x * 256 + threadIdx.x) * 4;
    if (i >= NOFF_) return;
    float4 s = *(const float4*)&part[i];
#pragma unroll
    for (int j = 1; j < 8; ++j) {
        float4 a = *(const float4*)&part[(size_t)j * NOFF_ + i];
        s.x += a.x; s.y += a.y; s.z += a.z; s.w += a.w;
    }
    int co = (i / HW_) & 7;
    float bb = b_off[co];
    float4 r;
    r.x = tanhf(s.x + bb);
    r.y = tanhf(s.y + bb);
    r.z = tanhf(s.z + bb);
    r.w = tanhf(s.w + bb);
    *(float4*)&off[i] = r;
}

// ---------------------------------------------------------------------------
// Kernel 3: 1x1 conv + folded BN + SiLU -> p.
// Block = 64 co x 128 pos, 128 threads (2 waves). Grid 1024 = 16b x 32pt x 2cot.
// Thread = 8co x 8pos, split (cob, cob+32) x (pb, pb+64): 4 b128 per 64 FMA
// (16 FMA/b128, 2x prev) and 16-B-stride lane pattern = <=2-way banks (free).
// ---------------------------------------------------------------------------
__global__ __launch_bounds__(128) void conv_proj(const float* __restrict__ x,
                                                 const float* __restrict__ wT,
                                                 const float* __restrict__ b2,
                                                 float* __restrict__ p) {
    int bx  = blockIdx.x;            // 1024 blocks
    int cot = bx & 1;                // 64-co half
    int pt  = (bx >> 1) & 31;        // pos tile (128 pos)
    int b   = bx >> 6;
    int pos0 = pt * 128;
    int t = threadIdx.x;             // 0..127
    int cob = (t >> 4) * 4;          // 0..28
    int pb  = (t & 15) * 4;          // 0..60

    __shared__ float xs[16][128];
    __shared__ float wsh[16][64];

    float acc[8][8];
#pragma unroll
    for (int i = 0; i < 8; ++i)
#pragma unroll
        for (int j = 0; j < 8; ++j) acc[i][j] = 0.f;

    for (int k0 = 0; k0 < C_; k0 += 16) {
        __syncthreads();
        // stage xs: 512 quads, 4 per thread
#pragma unroll
        for (int j = 0; j < 4; ++j) {
            int idx = j * 128 + t;
            int k = idx >> 5, pq = (idx & 31) * 4;
            *(float4*)&xs[k][pq] = *(const float4*)&x[(size_t)(b * C_ + k0 + k) * HW_ + pos0 + pq];
        }
        // stage wsh: 256 quads, 2 per thread
#pragma unroll
        for (int j = 0; j < 2; ++j) {
            int idx = j * 128 + t;
            int k = idx >> 4, cq = (idx & 15) * 4;
            *(float4*)&wsh[k][cq] = *(const float4*)&wT[(size_t)(k0 + k) * C_ + cot * 64 + cq];
        }
        __syncthreads();
#pragma unroll
        for (int k = 0; k < 16; ++k) {
            float4 xv0 = *(float4*)&xs[k][pb];
            float4 xv1 = *(float4*)&xs[k][pb + 64];
            float4 w0  = *(float4*)&wsh[k][cob];
            float4 w1  = *(float4*)&wsh[k][cob + 32];
            float xa[8] = {xv0.x, xv0.y, xv0.z, xv0.w, xv1.x, xv1.y, xv1.z, xv1.w};
            float wa[8] = {w0.x, w0.y, w0.z, w0.w, w1.x, w1.y, w1.z, w1.w};
#pragma unroll
            for (int co = 0; co < 8; ++co)
#pragma unroll
                for (int j = 0; j < 8; ++j)
                    acc[co][j] += wa[co] * xa[j];
        }
    }
#pragma unroll
    for (int co = 0; co < 8; ++co) {
        int cog = cot * 64 + ((co < 4) ? (cob + co) : (cob + 32 + co - 4));
        float bb = b2[cog];
        float v[8];
#pragma unroll
        for (int j = 0; j < 8; ++j) {
            float a = acc[co][j] + bb;
            v[j] = a / (1.f + __expf(-a));
        }
        float* dst = &p[(size_t)(b * C_ + cog) * HW_ + pos0];
        *(float4*)&dst[pb]      = make_float4(v[0], v[1], v[2], v[3]);
        *(float4*)&dst[pb + 64] = make_float4(v[4], v[5], v[6], v[7]);
    }
}

// ---------------------------------------------------------------------------
// Kernel 4: upsample offsets + grid_sample via LDS-staged 3-row slab.
// Slab bound proof (verified R8): iy in [rp-0.99, rp+0.99] -> rows rp-1..rp+1.
// Gathers drop the min-clamps on sx1/ry1: the clamped cases have exactly
// zero bilinear weight, and the flat +pad LDS (zeroed tail) keeps every wild
// read finite. Pairs (base,base+1,base+64,base+65) merge to ds_read2_b32.
// ---------------------------------------------------------------------------
__global__ __launch_bounds__(256) void dysample(const float* __restrict__ p,
                                                const float* __restrict__ off,
                                                float* __restrict__ out) {
    int bx = blockIdx.x;
    int rp = bx & 63;
    int g  = (bx >> 6) & 3;
    int b  = bx >> 8;
    int t  = threadIdx.x;

    __shared__ float lsf[CG_ * 3 * 64 + 4];   // flat [ch][row][col] + zeroed pad

    // stage rows rp-1..rp+1 (row-clamped) of the 32-channel group slab
    const float* pg = p + (size_t)(b * C_ + g * CG_) * HW_;
#pragma unroll
    for (int it = 0; it < 6; ++it) {
        int f = it * 256 + t;          // 0..1535 = 32ch * 3rows * 16 quads
        int ch = f / 48;
        int rem = f - ch * 48;
        int rw_ = rem >> 4;
        int wq = (rem & 15) << 2;
        int grow = min(max(rp - 1 + rw_, 0), 63);
        float4 v = *(const float4*)&pg[(size_t)ch * HW_ + grow * 64 + wq];
        *(float4*)&lsf[(ch * 3 + rw_) * 64 + wq] = v;
    }
    if (t < 4) lsf[CG_ * 3 * 64 + t] = 0.f;

    int ys = rp * 2 + (t >> 7);
    int xsid = t & 127;

    // bilinear-upsample the two offset planes at (ys, xsid)
    const float rw = 63.0f / 127.0f;
    float py = ys * rw;
    int uy0 = (int)floorf(py);
    float fy = py - (float)uy0;
    int uy1 = min(uy0 + 1, 63);
    float pxf = xsid * rw;
    int ux0 = (int)floorf(pxf);
    float fx = pxf - (float)ux0;
    int ux1 = min(ux0 + 1, 63);

    const float* o0 = off + (size_t)(b * 8 + 2 * g) * HW_;
    const float* o1 = o0 + HW_;
    float ox, oy;
    {
        float a00 = o0[uy0 * 64 + ux0], a01 = o0[uy0 * 64 + ux1];
        float a10 = o0[uy1 * 64 + ux0], a11 = o0[uy1 * 64 + ux1];
        float t0 = a00 * (1.f - fy) + a10 * fy;
        float t1 = a01 * (1.f - fy) + a11 * fy;
        ox = t0 * (1.f - fx) + t1 * fx;
    }
    {
        float a00 = o1[uy0 * 64 + ux0], a01 = o1[uy0 * 64 + ux1];
        float a10 = o1[uy1 * 64 + ux0], a11 = o1[uy1 * 64 + ux1];
        float t0 = a00 * (1.f - fy) + a10 * fy;
        float t1 = a01 * (1.f - fy) + a11 * fy;
        oy = t0 * (1.f - fx) + t1 * fx;
    }

    float gx = (-1.f + xsid * (2.0f / 127.0f)) + ox * (2.0f / 128.0f);
    float gy = (-1.f + ys   * (2.0f / 127.0f)) + oy * (2.0f / 128.0f);

    float ix = fminf(fmaxf((gx + 1.f) * 0.5f * 63.f, 0.f), 63.f);
    float iy = fminf(fmaxf((gy + 1.f) * 0.5f * 63.f, 0.f), 63.f);
    int sx0 = (int)floorf(ix);
    float wx = ix - (float)sx0;       // = 0 exactly when sx0 == 63
    int sy0 = (int)floorf(iy);
    float wy = iy - (float)sy0;       // = 0 exactly when sy0 == 63

    int ry0 = sy0 - rp + 1;           // in {0,1} by the bound proof

    float w00 = (1.f - wx) * (1.f - wy), w01 = wx * (1.f - wy);
    float w10 = (1.f - wx) * wy,         w11 = wx * wy;

    __syncthreads();

    float* obase = out + (size_t)(b * C_ + g * CG_) * HWS_ + ys * WS_ + xsid;
#pragma unroll 8
    for (int c = 0; c < CG_; ++c) {
        int base = (c * 3 + ry0) * 64 + sx0;
        float v00 = lsf[base],      v01 = lsf[base + 1];
        float v10 = lsf[base + 64], v11 = lsf[base + 65];
        float r = v00 * w00 + v01 * w01 + v10 * w10 + v11 * w11;
        __builtin_nontemporal_store(r, &obase[(size_t)c * HWS_]);
    }
}

// ---------------------------------------------------------------------------
extern "C" void kernel_launch(void* const* d_in, const int* in_sizes, int n_in,
                              void* d_out, int out_size, void* d_ws, size_t ws_size,
                              hipStream_t stream) {
    const float* x      = (const float*)d_in[0];
    const float* w_off  = (const float*)d_in[1];
    const float* b_off  = (const float*)d_in[2];
    const float* w_proj = (const float*)d_in[3];
    const float* bn_g   = (const float*)d_in[4];
    const float* bn_b   = (const float*)d_in[5];
    const float* bn_m   = (const float*)d_in[6];
    const float* bn_v   = (const float*)d_in[7];
    float* out = (float*)d_out;
    float* ws  = (float*)d_ws;

    // ws layout (floats). part (16MB) dead before p (32MB) written -> alias.
    float* p    = ws;                 // 8,388,608 floats
    float* part = ws;                 // 4,194,304 floats (aliased with p)
    float* offb = ws + 8388608;       //   524,288
    float* wT   = ws + 8912896;       //    16,384
    float* b2   = ws + 8929280;       //       128

    prep_w    <<<65,   256, 0, stream>>>(w_proj, bn_g, bn_b, bn_m, bn_v, wT, b2);
    conv_off  <<<1024, 256, 0, stream>>>(x, w_off, part);
    off_reduce<<<512,  256, 0, stream>>>(part, b_off, offb);
    conv_proj <<<1024, 128, 0, stream>>>(x, wT, b2, p);
    dysample  <<<4096, 256, 0, stream>>>(p, offb, out);
}